// Round 8
// baseline (448.984 us; speedup 1.0000x reference)
//
#include <hip/hip_runtime.h>
#include <stdint.h>

// out[b,s,u] = (LN(x) @ ternary(W)) * mean|W|   (reference's gamma absmax cancels)
// Fused: absum -> ternarize into MFMA-frag-packed wqP -> [LN + i8 quant + barrier-free GEMM].
// Round 6: phase-2 restructure. Fully-unrolled straight-line K loop (no loop-carried
// waitcnt conservatism), 4 independent acc chains (2mf x 2nb), 2 passes (half the
// boundary drains), next-pass B prologue issued before the epilogue stores.
// x: (4,8192,1024) fp32. M=32768, K=1024, N=1024, out fp32.

#define M_ROWS 32768
#define KDIM 1024
#define NDIM 1024

typedef int v4i  __attribute__((ext_vector_type(4)));
typedef int v16i __attribute__((ext_vector_type(16)));

#define MFMA_I8 __builtin_amdgcn_mfma_i32_32x32x32_i8

// ---------------- kernel 1: |w| partial sums (no atomics, no memset) ------------
__global__ __launch_bounds__(256) void absum_k(const float* __restrict__ w,
                                               float* __restrict__ partials) {
    int idx = blockIdx.x * 256 + threadIdx.x;
    float4 v = ((const float4*)w)[idx];
    float s = fabsf(v.x) + fabsf(v.y) + fabsf(v.z) + fabsf(v.w);
    #pragma unroll
    for (int o = 32; o; o >>= 1) s += __shfl_xor(s, o);
    __shared__ float p[4];
    if ((threadIdx.x & 63) == 0) p[threadIdx.x >> 6] = s;
    __syncthreads();
    if (threadIdx.x == 0) partials[blockIdx.x] = p[0] + p[1] + p[2] + p[3];
}

// ------- kernel 2: ternarize -> wqP packed MFMA-frag-major ----------------------
// Frag (nb, s): lane l holds B[n=nb*32+(l&31)][k=s*32+(l>>5)*16 .. +16], stored as
// 64 contiguous 16B units at wqP[((nb*32+s)*64 + l)*16]. One wave-load = 1KB linear.
__global__ __launch_bounds__(256) void quant_k(const float* __restrict__ w,
                                               const float* __restrict__ partials,
                                               char* __restrict__ wqP,
                                               float* __restrict__ wsum) {
    int t = threadIdx.x;
    float s = partials[t] + partials[t + 256] + partials[t + 512] + partials[t + 768];
    #pragma unroll
    for (int o = 32; o; o >>= 1) s += __shfl_xor(s, o);
    __shared__ float ps[4];
    if ((t & 63) == 0) ps[t >> 6] = s;
    __syncthreads();
    float total = ps[0] + ps[1] + ps[2] + ps[3];
    if (blockIdx.x == 0 && t == 0) wsum[0] = total;
    float beta = total * (1.0f / 1048576.0f);
    float inv  = 1.0f / (beta + 1e-5f);

    __shared__ char sT[64 * 80];           // [n][k], stride 80 (16B-aligned rows)
    int k0 = (blockIdx.x >> 4) * 64, n0 = (blockIdx.x & 15) * 64;
    int n_l = t & 63;
    #pragma unroll
    for (int r = 0; r < 16; ++r) {
        int k_l = (t >> 6) * 16 + r;
        float q = rintf(w[(size_t)(k0 + k_l) * NDIM + n0 + n_l] * inv);
        q = fminf(1.0f, fmaxf(-1.0f, q));
        sT[n_l * 80 + k_l] = (char)(int)q;
    }
    __syncthreads();
    int nn = t >> 2, c = t & 3;
    v4i val = *(const v4i*)&sT[nn * 80 + c * 16];
    int n = n0 + nn, k = k0 + c * 16;
    int idx = ((n >> 5) * 32 + (k >> 5)) * 64 + (n & 31) + ((k >> 4) & 1) * 32;
    *(v4i*)&wqP[(size_t)idx * 16] = val;
}

// ---------------- kernel 3: fused LN + i8 quant + barrier-free i8 GEMM ----------
// 512 thr (8 waves), BM=64, full N=1024; LDS 64KB sA -> 2 blocks/CU = 4 waves/SIMD.
// Budget/wave (4 waves/SIMD) = 128 unified regs: 64 acc (4 chains) + ~55 arch.
// sA frag-major: unit u = k/16, 32 slots x 16B, slot = (row&31) ^ (u&7) -> both
// char4 writes (2-way, free) and ds_read_b128 frag reads are conflict-free.
// Phase 2: ONE barrier total; 2 passes; wave owns 64m x 64n/pass (nb0=p*16+w*2,+1);
// K loop FULLY UNROLLED: straight-line lets the compiler emit counted waitcnts and
// pipeline loads ~depth-4. B rolling slots reloaded 8 MFMAs before reuse (~293 cy).
__global__ __launch_bounds__(512, 4) void ln_gemm_k(const float* __restrict__ x,
                                                    const float* __restrict__ g,
                                                    const float* __restrict__ bln,
                                                    const char* __restrict__ wqP,
                                                    const float* __restrict__ wsum,
                                                    float* __restrict__ out) {
    __shared__ char  sA[64 * 1024];
    __shared__ float sScl[64];

    int t = threadIdx.x;
    int w = t >> 6, lane = t & 63;
    int half = lane >> 5, l31 = lane & 31;
    int bm0 = blockIdx.x * 64;

    const v4i* wp = (const v4i*)wqP;
    size_t fb = (size_t)w * 4096 + lane;     // pass-0 frag base: nb0 = w*2
    // pass-0 B prologue issued before the barrier: overlaps phase-1 tail
    v4i bX0 = wp[fb],        bX1 = wp[fb + 2048];        // frag(nb0,0), frag(nb1,0)
    v4i bY0 = wp[fb + 64],   bY1 = wp[fb + 2048 + 64];   // frag(nb0,1), frag(nb1,1)

    // ---- phase 1: LN + per-row quant into frag-major sA (wave: 8 rows) ----
    #pragma unroll 1
    for (int rr = 0; rr < 8; ++rr) {
        int row = w * 8 + rr;
        const float4* xr = (const float4*)(x + ((size_t)(bm0 + row) << 10));
        float4 v0 = xr[lane], v1 = xr[lane + 64], v2 = xr[lane + 128], v3 = xr[lane + 192];
        float s  = v0.x + v0.y + v0.z + v0.w + v1.x + v1.y + v1.z + v1.w
                 + v2.x + v2.y + v2.z + v2.w + v3.x + v3.y + v3.z + v3.w;
        float ss = v0.x*v0.x + v0.y*v0.y + v0.z*v0.z + v0.w*v0.w
                 + v1.x*v1.x + v1.y*v1.y + v1.z*v1.z + v1.w*v1.w
                 + v2.x*v2.x + v2.y*v2.y + v2.z*v2.z + v2.w*v2.w
                 + v3.x*v3.x + v3.y*v3.y + v3.z*v3.z + v3.w*v3.w;
        #pragma unroll
        for (int o = 32; o; o >>= 1) { s += __shfl_xor(s, o); ss += __shfl_xor(ss, o); }
        float mu  = s * (1.0f / 1024.0f);
        float var = ss * (1.0f / 1024.0f) - mu * mu;
        float rs  = rsqrtf(var + 1e-3f);        // keras LN eps
        float xn[16];
        float4 vv[4] = {v0, v1, v2, v3};
        float mx = 0.f;
        #pragma unroll
        for (int j = 0; j < 4; ++j) {           // gamma/beta loaded per-j: L1-hot,
            float4 gg = ((const float4*)g)[lane + 64 * j];   // keeps peak regs low
            float4 bb = ((const float4*)bln)[lane + 64 * j];
            xn[4*j+0] = (vv[j].x - mu) * rs * gg.x + bb.x;
            xn[4*j+1] = (vv[j].y - mu) * rs * gg.y + bb.y;
            xn[4*j+2] = (vv[j].z - mu) * rs * gg.z + bb.z;
            xn[4*j+3] = (vv[j].w - mu) * rs * gg.w + bb.w;
            #pragma unroll
            for (int e = 0; e < 4; ++e) mx = fmaxf(mx, fabsf(xn[4*j+e]));
        }
        #pragma unroll
        for (int o = 32; o; o >>= 1) mx = fmaxf(mx, __shfl_xor(mx, o));
        mx = fmaxf(mx, 1e-20f);
        float inv = 127.0f / mx;
        if (lane == 0) sScl[row] = mx * (1.0f / 127.0f);
        int mf = row >> 5, r31 = row & 31;
        #pragma unroll
        for (int j = 0; j < 4; ++j) {
            // lane's float4 j covers k = 4*(lane + 64j) .. +3 -> one char4
            char4 c4;
            c4.x = (char)(int)rintf(xn[4*j+0] * inv);
            c4.y = (char)(int)rintf(xn[4*j+1] * inv);
            c4.z = (char)(int)rintf(xn[4*j+2] * inv);
            c4.w = (char)(int)rintf(xn[4*j+3] * inv);
            int u    = (lane >> 2) + 16 * j;          // 16B unit = k>>4
            int slot = r31 ^ (u & 7);
            *(char4*)&sA[mf * 32768 + (u * 32 + slot) * 16 + (lane & 3) * 4] = c4;
        }
    }
    __syncthreads();                              // the ONLY barrier

    // ---- phase 2: barrier-free GEMM, fully-unrolled K, 4 acc chains. ----
    float beta = wsum[0] * (1.0f / 1048576.0f);

    // A frag (both mf blocks) for k-step S: unit u = 2S+half, slot = l31 ^ (u&7)
    #define LA2(dst, S) do { \
        int u_ = 2 * (S) + half; \
        int o_ = ((u_ * 32) + (l31 ^ (u_ & 7))) * 16; \
        dst[0] = *(const v4i*)&sA[o_]; \
        dst[1] = *(const v4i*)&sA[o_ + 32768]; \
    } while (0)

    #pragma unroll 1
    for (int p = 0; p < 2; ++p) {
        v16i a00 = {}, a01 = {}, a10 = {}, a11 = {};
        v4i aX[2], aY[2];
        LA2(aX, 0); LA2(aY, 1);

        #pragma unroll
        for (int s = 0; s < 32; s += 2) {
            // even k-step: aX with bX0 (nb0) and bX1 (nb1)
            a00 = MFMA_I8(aX[0], bX0, a00, 0, 0, 0);
            a10 = MFMA_I8(aX[1], bX0, a10, 0, 0, 0);
            if (s < 30) bX0 = wp[fb + (size_t)(s + 2) * 64];
            a01 = MFMA_I8(aX[0], bX1, a01, 0, 0, 0);
            a11 = MFMA_I8(aX[1], bX1, a11, 0, 0, 0);
            if (s < 30) bX1 = wp[fb + 2048 + (size_t)(s + 2) * 64];
            if (s < 30) LA2(aX, s + 2);
            // odd k-step: aY with bY0, bY1
            a00 = MFMA_I8(aY[0], bY0, a00, 0, 0, 0);
            a10 = MFMA_I8(aY[1], bY0, a10, 0, 0, 0);
            if (s < 30) bY0 = wp[fb + (size_t)(s + 3) * 64];
            a01 = MFMA_I8(aY[0], bY1, a01, 0, 0, 0);
            a11 = MFMA_I8(aY[1], bY1, a11, 0, 0, 0);
            if (s < 30) bY1 = wp[fb + 2048 + (size_t)(s + 3) * 64];
            if (s < 30) LA2(aY, s + 3);
        }

        // next pass's B prologue BEFORE the epilogue stores: store-issue covers latency
        if (p == 0) {
            fb += 32768;                          // nb0: w*2 -> 16 + w*2
            bX0 = wp[fb];      bX1 = wp[fb + 2048];
            bY0 = wp[fb + 64]; bY1 = wp[fb + 2048 + 64];
        }

        // epilogue: 2mf x 2nb x 16
        int nb0 = p * 16 + w * 2;
        #pragma unroll
        for (int r = 0; r < 16; ++r) {
            // C/D 32x32: col = lane&31, row = (r&3) + 8*(r>>2) + 4*(lane>>5)
            int rl = (r & 3) + 8 * (r >> 2) + 4 * half;
            float sc0 = sScl[rl] * beta;
            float sc1 = sScl[32 + rl] * beta;
            size_t o0 = (size_t)(bm0 + rl) * NDIM + nb0 * 32 + l31;
            size_t o1 = o0 + (size_t)32 * NDIM;
            out[o0]      = (float)a00[r] * sc0;
            out[o0 + 32] = (float)a01[r] * sc0;
            out[o1]      = (float)a10[r] * sc1;
            out[o1 + 32] = (float)a11[r] * sc1;
        }
    }
    #undef LA2
}

extern "C" void kernel_launch(void* const* d_in, const int* in_sizes, int n_in,
                              void* d_out, int out_size, void* d_ws, size_t ws_size,
                              hipStream_t stream) {
    const float* x        = (const float*)d_in[0];   // 4*8192*1024
    const float* weight   = (const float*)d_in[1];   // 1024*1024
    const float* ln_gamma = (const float*)d_in[2];   // 1024
    const float* ln_beta  = (const float*)d_in[3];   // 1024
    float* out = (float*)d_out;

    // ws layout: [0,4) wsum | [4K, 8K) partials(1024 f32) | [256K, 256K+1M) wqP i8
    float* wsum     = (float*)d_ws;
    float* partials = (float*)((char*)d_ws + 4096);
    char*  wqP      = (char*)d_ws + (1u << 18);

    absum_k<<<1024, 256, 0, stream>>>(weight, partials);
    quant_k<<<256, 256, 0, stream>>>(weight, partials, wqP, wsum);
    ln_gemm_k<<<M_ROWS / 64, 512, 0, stream>>>(x, ln_gamma, ln_beta, wqP, wsum, out);
}

// Round 9
// 276.746 us; speedup vs baseline: 1.6224x; 1.6224x over previous
//
#include <hip/hip_runtime.h>
#include <stdint.h>

// out[b,s,u] = (LN(x) @ ternary(W)) * mean|W|   (reference's gamma absmax cancels)
// Round 9: back to the measured-champion SPLIT pipeline (R2, 271us), with gemm_k
// tile 128x128 -> 256x128: 32 MFMA per barrier-pair (was 16), half the drains,
// 2x A-panel L2 reuse. All other kernels verbatim from the validated champion.
// x: (4,8192,1024) fp32 -> M=32768, K=1024, N=1024, out fp32.

#define M_ROWS 32768
#define KDIM 1024
#define NDIM 1024

typedef int   v4i  __attribute__((ext_vector_type(4)));
typedef int   v16i __attribute__((ext_vector_type(16)));

#define MFMA_I8 __builtin_amdgcn_mfma_i32_32x32x32_i8

__device__ __forceinline__ void async16(const void* g, void* l) {
    __builtin_amdgcn_global_load_lds((const __attribute__((address_space(1))) uint32_t*)g,
                                     (__attribute__((address_space(3))) uint32_t*)l,
                                     16, 0, 0);
}

// ---------------- kernel 1: |w| partial sums (no atomics, no memset) ------------
__global__ __launch_bounds__(256) void absum_k(const float* __restrict__ w,
                                               float* __restrict__ partials) {
    int idx = blockIdx.x * 256 + threadIdx.x;
    float4 v = ((const float4*)w)[idx];
    float s = fabsf(v.x) + fabsf(v.y) + fabsf(v.z) + fabsf(v.w);
    #pragma unroll
    for (int o = 32; o; o >>= 1) s += __shfl_xor(s, o);
    __shared__ float p[4];
    if ((threadIdx.x & 63) == 0) p[threadIdx.x >> 6] = s;
    __syncthreads();
    if (threadIdx.x == 0) partials[blockIdx.x] = p[0] + p[1] + p[2] + p[3];
}

// ---------------- kernel 2: ternarize + transpose -> wqT[n][k] i8 ---------------
__global__ __launch_bounds__(256) void quant_k(const float* __restrict__ w,
                                               const float* __restrict__ partials,
                                               char* __restrict__ wqT,
                                               float* __restrict__ wsum) {
    int t = threadIdx.x;
    float s = partials[t] + partials[t + 256] + partials[t + 512] + partials[t + 768];
    #pragma unroll
    for (int o = 32; o; o >>= 1) s += __shfl_xor(s, o);
    __shared__ float ps[4];
    if ((t & 63) == 0) ps[t >> 6] = s;
    __syncthreads();
    float total = ps[0] + ps[1] + ps[2] + ps[3];
    if (blockIdx.x == 0 && t == 0) wsum[0] = total;
    float beta = total * (1.0f / 1048576.0f);
    float inv  = 1.0f / (beta + 1e-5f);

    __shared__ char sT[64 * 80];           // [n][k], stride 80 (16B-aligned rows)
    int k0 = (blockIdx.x >> 4) * 64, n0 = (blockIdx.x & 15) * 64;
    int n_l = t & 63;
    #pragma unroll
    for (int r = 0; r < 16; ++r) {
        int k_l = (t >> 6) * 16 + r;
        float q = rintf(w[(size_t)(k0 + k_l) * NDIM + n0 + n_l] * inv);
        q = fminf(1.0f, fmaxf(-1.0f, q));
        sT[n_l * 80 + k_l] = (char)(int)q;
    }
    __syncthreads();
    int nn = t >> 2, c = t & 3;
    v4i val = *(const v4i*)&sT[nn * 80 + c * 16];
    *(v4i*)&wqT[(size_t)(n0 + nn) * KDIM + k0 + c * 16] = val;
}

// ---------------- kernel 3: LN + per-row i8 quant, wave-per-row, one pass -------
__global__ __launch_bounds__(256) void ln_q_k(const float* __restrict__ x,
                                              const float* __restrict__ g,
                                              const float* __restrict__ b,
                                              char* __restrict__ xq,
                                              float* __restrict__ rscale) {
    int tid = threadIdx.x;
    int lane = tid & 63;
    int row = blockIdx.x * 4 + (tid >> 6);
    const float4* xr = (const float4*)(x + (size_t)row * KDIM);
    float4 v[4];
    #pragma unroll
    for (int j = 0; j < 4; ++j) v[j] = xr[lane + 64 * j];
    float s = 0.f, ss = 0.f;
    #pragma unroll
    for (int j = 0; j < 4; ++j) {
        s  += v[j].x + v[j].y + v[j].z + v[j].w;
        ss += v[j].x * v[j].x + v[j].y * v[j].y + v[j].z * v[j].z + v[j].w * v[j].w;
    }
    #pragma unroll
    for (int o = 32; o; o >>= 1) { s += __shfl_xor(s, o); ss += __shfl_xor(ss, o); }
    float mu  = s * (1.0f / 1024.0f);
    float var = ss * (1.0f / 1024.0f) - mu * mu;
    float rs  = rsqrtf(var + 1e-3f);        // keras LN eps
    float xn[16];
    float mx = 0.f;
    #pragma unroll
    for (int j = 0; j < 4; ++j) {
        int p = lane + 64 * j;
        float4 gg = ((const float4*)g)[p];
        float4 bb = ((const float4*)b)[p];
        xn[4*j+0] = (v[j].x - mu) * rs * gg.x + bb.x;
        xn[4*j+1] = (v[j].y - mu) * rs * gg.y + bb.y;
        xn[4*j+2] = (v[j].z - mu) * rs * gg.z + bb.z;
        xn[4*j+3] = (v[j].w - mu) * rs * gg.w + bb.w;
        #pragma unroll
        for (int e = 0; e < 4; ++e) mx = fmaxf(mx, fabsf(xn[4*j+e]));
    }
    #pragma unroll
    for (int o = 32; o; o >>= 1) mx = fmaxf(mx, __shfl_xor(mx, o));
    mx = fmaxf(mx, 1e-20f);
    float scl = mx * (1.0f / 127.0f);
    float inv = 127.0f / mx;
    if (lane == 0) rscale[row] = scl;
    #pragma unroll
    for (int j = 0; j < 4; ++j) {
        char4 c;
        c.x = (char)(int)rintf(xn[4*j+0] * inv);
        c.y = (char)(int)rintf(xn[4*j+1] * inv);
        c.z = (char)(int)rintf(xn[4*j+2] * inv);
        c.w = (char)(int)rintf(xn[4*j+3] * inv);
        *(char4*)(xq + (size_t)row * KDIM + (lane + 64 * j) * 4) = c;
    }
}

// ---------------- kernel 4: i8 GEMM  out = (xq @ wqT^T) * rscale[m] * beta ------
// A: [M][K] i8, B: [N][K] i8, out [M][N] f32. 256x128 tile, BK=128 (8 k-iters),
// 256 thr = 4 waves as 2m x 2n; wave = 128m x 64n via 4x2 of 32x32x32 i8 MFMA.
// 32 MFMA per barrier-pair (2x the 128^2 champion), half the drain events.
// Same validated 128-byte-row / 8-chunk XOR-swizzled LDS geometry + async16
// pre-swizzled-source staging. LDS 48 KB, ~218 regs -> 2 blocks/CU.
__global__ __launch_bounds__(256) void gemm_k(const char* __restrict__ A,
                                              const char* __restrict__ B,
                                              const float* __restrict__ wsum,
                                              const float* __restrict__ rscale,
                                              float* __restrict__ out) {
    __shared__ char sA[256 * 128];
    __shared__ char sB[128 * 128];
    int tid = threadIdx.x;
    int w = tid >> 6, lane = tid & 63;
    int half = lane >> 5, l31 = lane & 31;
    int wm = w >> 1, wn = w & 1;
    int xcd   = blockIdx.x & 7;              // round-robin across 8 XCDs
    int local = blockIdx.x >> 3;             // 0..127 within this XCD
    int bm0 = (xcd * 16 + (local >> 3)) * 256;   // disjoint 256-row panel per XCD
    int bn0 = (local & 7) * 128;                 // bn innermost -> A L2 reuse

    v16i acc[4][2] = {};

    int r_sub = lane >> 3;   // row within the 8-row staging slab
    int p     = lane & 7;    // stored chunk position

    for (int kt = 0; kt < 8; ++kt) {
        int k0 = kt * 128;
        #pragma unroll
        for (int t = 0; t < 8; ++t) {        // A: 256 rows = 4 waves x 8 slabs x 8 rows
            int rb  = w * 64 + t * 8;        // wave-uniform LDS base row
            int row = rb + r_sub;
            int c   = p ^ (row & 7);         // chunk-XOR swizzle (pre-swizzled source)
            async16(A + (size_t)(bm0 + row) * KDIM + k0 + c * 16, &sA[rb * 128]);
        }
        #pragma unroll
        for (int t = 0; t < 4; ++t) {        // B: 128 rows = 4 waves x 4 slabs x 8 rows
            int rb  = w * 32 + t * 8;
            int row = rb + r_sub;
            int c   = p ^ (row & 7);
            async16(B + (size_t)(bn0 + row) * KDIM + k0 + c * 16, &sB[rb * 128]);
        }
        __syncthreads();
        #pragma unroll
        for (int kk = 0; kk < 4; ++kk) {
            v4i af[4], bf[2];
            int c16 = kk * 2 + half;         // 16B chunk holding this lane's k-run
            #pragma unroll
            for (int i = 0; i < 4; ++i) {
                int m = wm * 128 + i * 32 + l31;
                af[i] = *(const v4i*)&sA[m * 128 + ((c16 ^ (m & 7)) << 4)];
            }
            #pragma unroll
            for (int j = 0; j < 2; ++j) {
                int n = wn * 64 + j * 32 + l31;
                bf[j] = *(const v4i*)&sB[n * 128 + ((c16 ^ (n & 7)) << 4)];
            }
            #pragma unroll
            for (int i = 0; i < 4; ++i)
                #pragma unroll
                for (int j = 0; j < 2; ++j)
                    acc[i][j] = MFMA_I8(af[i], bf[j], acc[i][j], 0, 0, 0);
        }
        __syncthreads();
    }

    float beta = wsum[0] * (1.0f / 1048576.0f);
    #pragma unroll
    for (int i = 0; i < 4; ++i) {
        #pragma unroll
        for (int r = 0; r < 16; ++r) {
            // C/D 32x32: col = lane&31, row = (r&3) + 8*(r>>2) + 4*(lane>>5)
            int mrow = bm0 + wm * 128 + i * 32 + (r & 3) + 8 * (r >> 2) + 4 * half;
            float sc = rscale[mrow] * beta;
            #pragma unroll
            for (int j = 0; j < 2; ++j) {
                int ncol = bn0 + wn * 64 + j * 32 + l31;
                out[(size_t)mrow * NDIM + ncol] = (float)acc[i][j][r] * sc;
            }
        }
    }
}

extern "C" void kernel_launch(void* const* d_in, const int* in_sizes, int n_in,
                              void* d_out, int out_size, void* d_ws, size_t ws_size,
                              hipStream_t stream) {
    const float* x        = (const float*)d_in[0];   // 4*8192*1024
    const float* weight   = (const float*)d_in[1];   // 1024*1024
    const float* ln_gamma = (const float*)d_in[2];   // 1024
    const float* ln_beta  = (const float*)d_in[3];   // 1024
    float* out = (float*)d_out;

    // ws layout: [0,4) wsum | [4K, 8K) partials(1024 f32) | [8K, 136K) rscale(32768 f32)
    //            [256K, 256K+1M) wqT i8 | [2M, 2M+32M) xq i8
    float* wsum     = (float*)d_ws;
    float* partials = (float*)((char*)d_ws + 4096);
    float* rscale   = (float*)((char*)d_ws + 8192);
    char*  wqT      = (char*)d_ws + (1u << 18);
    char*  xq       = (char*)d_ws + (1u << 21);

    absum_k<<<1024, 256, 0, stream>>>(weight, partials);
    quant_k<<<256, 256, 0, stream>>>(weight, partials, wqT, wsum);
    ln_q_k<<<M_ROWS / 4, 256, 0, stream>>>(x, ln_gamma, ln_beta, xq, rscale);
    gemm_k<<<(M_ROWS / 256) * (NDIM / 128), 256, 0, stream>>>(xq, wqT, wsum, rscale, out);
}